// Round 6
// baseline (93.819 us; speedup 1.0000x reference)
//
#include <hip/hip_runtime.h>
#include <stdint.h>

using i32x4  = __attribute__((ext_vector_type(4))) int;
using i32x16 = __attribute__((ext_vector_type(16))) int;

// ---------------- ws layout ----------------
#define WS_SCALED   2048
#define WS_SCALEF   2056
#define WS_FACT     4096
#define WS_XQ       (1u << 20)
#define WS_QW       ((1u << 20) + (32u << 20))

// ---------------- kernel 1: fused aquant (blocks 0..8191) + wabs partials (8192..8447) ----
__device__ inline int q8pack(float4 f, float as) {
    int a = (int)fminf(fmaxf(rintf(f.x * as), -128.0f), 127.0f);
    int b = (int)fminf(fmaxf(rintf(f.y * as), -128.0f), 127.0f);
    int c = (int)fminf(fmaxf(rintf(f.z * as), -128.0f), 127.0f);
    int d = (int)fminf(fmaxf(rintf(f.w * as), -128.0f), 127.0f);
    return (a & 0xff) | ((b & 0xff) << 8) | ((c & 0xff) << 16) | ((d & 0xff) << 24);
}

__global__ __launch_bounds__(256) void k_fused1(const float* __restrict__ x,
                                                const float* __restrict__ w,
                                                int8_t* __restrict__ xq,
                                                float* __restrict__ fact,
                                                double* __restrict__ partials) {
    int t = threadIdx.x;
    if (blockIdx.x >= 8192) {
        int b = blockIdx.x - 8192;
        const float4* w4 = (const float4*)(w + b * 4096);
        double s = 0.0;
#pragma unroll
        for (int i = 0; i < 4; ++i) {
            float4 v = w4[i * 256 + t];
            s += (double)fabsf(v.x) + (double)fabsf(v.y) +
                 (double)fabsf(v.z) + (double)fabsf(v.w);
        }
#pragma unroll
        for (int off = 32; off > 0; off >>= 1) s += __shfl_down(s, off, 64);
        __shared__ double lds[4];
        if ((t & 63) == 0) lds[t >> 6] = s;
        __syncthreads();
        if (t == 0) partials[b] = ((lds[0] + lds[1]) + (lds[2] + lds[3]));
        return;
    }
    int wid = t >> 6;
    int lane = t & 63;
    int token = blockIdx.x * 4 + wid;
    const float* xr = x + (size_t)token * 1024;
    float4 v[4];
    float m = 0.0f;
#pragma unroll
    for (int c = 0; c < 4; ++c) {
        v[c] = *(const float4*)(xr + c * 256 + lane * 4);
        m = fmaxf(m, fmaxf(fmaxf(fabsf(v[c].x), fabsf(v[c].y)),
                           fmaxf(fabsf(v[c].z), fabsf(v[c].w))));
    }
#pragma unroll
    for (int off = 32; off > 0; off >>= 1) m = fmaxf(m, __shfl_xor(m, off, 64));
    m = fmaxf(m, 1e-5f);
    float as = 127.0f / m;
    int* xqo = (int*)xq;
#pragma unroll
    for (int c = 0; c < 4; ++c)
        xqo[token * 256 + c * 64 + lane] = q8pack(v[c], as);
    if (lane == 0) fact[token] = 1.0f / as;
}

// ---------------- kernel 2: fused scale-reduce (redundant, deterministic) + wquant ----
__global__ __launch_bounds__(256) void k_fused2(const float* __restrict__ w,
                                                const double* __restrict__ partials,
                                                int8_t* __restrict__ qw,
                                                float* __restrict__ scale_f) {
    int t = threadIdx.x;
    double s = partials[t];
#pragma unroll
    for (int off = 32; off > 0; off >>= 1) s += __shfl_down(s, off, 64);
    __shared__ double lds[4];
    if ((t & 63) == 0) lds[t >> 6] = s;
    __syncthreads();
    __shared__ double sc_sh;
    if (t == 0) {
        double m = ((lds[0] + lds[1]) + (lds[2] + lds[3])) / 1048576.0;
        if (m < 1e-5) m = 1e-5;
        sc_sh = m;
        if (blockIdx.x == 0) *scale_f = (float)m;
    }
    __syncthreads();
    double half_s = 0.5 * sc_sh;

    int idx = blockIdx.x * 2048 + t * 8;
    float4 v0 = *(const float4*)(w + idx);
    float4 v1 = *(const float4*)(w + idx + 4);
    float f[8] = {v0.x, v0.y, v0.z, v0.w, v1.x, v1.y, v1.z, v1.w};
    union { char c[8]; int2 p; } u;
#pragma unroll
    for (int i = 0; i < 8; ++i) {
        char q = 0;
        if ((double)fabsf(f[i]) > half_s) q = (f[i] > 0.0f) ? 1 : -1;
        u.c[i] = q;
    }
    *(int2*)(qw + idx) = u.p;
}

// ---------------- kernel 3: i8 MFMA GEMM, 256x256, 8-phase, 32x32x32, LDS-staged stores ----
__device__ __forceinline__ void gl_lds16(const void* g, void* l) {
    __builtin_amdgcn_global_load_lds((const __attribute__((address_space(1))) void*)g,
                                     (__attribute__((address_space(3))) void*)l, 16, 0, 0);
}

#define PH32(MH, NH, BRS) \
    __builtin_amdgcn_s_barrier(); \
    asm volatile("s_waitcnt lgkmcnt(0)" ::: "memory"); \
    __builtin_amdgcn_sched_barrier(0); \
    __builtin_amdgcn_s_setprio(1); \
    _Pragma("unroll") \
    for (int ks = 0; ks < 4; ++ks) \
    _Pragma("unroll") \
    for (int mt = 0; mt < 2; ++mt) \
        acc[MH*2+mt][NH] = __builtin_amdgcn_mfma_i32_32x32x32_i8( \
            aR[mt][ks], BRS[ks], acc[MH*2+mt][NH], 0, 0, 0); \
    __builtin_amdgcn_s_setprio(0); \
    __builtin_amdgcn_s_barrier();

__global__ __launch_bounds__(512, 2) void k_gemm4(const int8_t* __restrict__ A,
                                                  const int8_t* __restrict__ B,
                                                  const float* __restrict__ fact,
                                                  const float* __restrict__ scale_f,
                                                  const float* __restrict__ bias,
                                                  float* __restrict__ out) {
    __shared__ int8_t smem[131072];   // K-loop: A0|A1|B0|B1 32 KB each; epilogue: float[128][256]

    const int tid  = threadIdx.x;
    const int lane = tid & 63;
    const int wid  = tid >> 6;
    const int wm   = wid >> 2;
    const int wn   = wid & 3;
    const int l31  = lane & 31;
    const int l5   = lane >> 5;

    int bid = blockIdx.x;
    int swz = (bid & 7) * 64 + (bid >> 3);
    int tm = swz >> 2;
    int tn = swz & 3;

    const int8_t* Ag = A + (size_t)tm * 256 * 1024;
    const int8_t* Bg = B + (size_t)tn * 256 * 1024;

    const int sr  = tid >> 3;
    const int ssl = tid & 7;

    auto stageA = [&](int bi, int r0, int kb) {
        int pr = r0 + sr;
        gl_lds16(Ag + (size_t)pr * 1024 + kb + ((ssl ^ (pr & 7)) << 4),
                 smem + bi * 32768 + r0 * 128 + tid * 16);
    };
    auto stageB = [&](int bi, int r0, int kb) {
        int pr = r0 + sr;
        int br = ((pr & 127) >> 5) * 64 + ((pr >> 7) << 5) + (pr & 31);
        gl_lds16(Bg + (size_t)br * 1024 + kb + ((ssl ^ (pr & 7)) << 4),
                 smem + 65536 + bi * 32768 + r0 * 128 + tid * 16);
    };
    auto ldA32 = [&](int bi, int mh, int mt, int ks) -> i32x4 {
        int r  = wm * 128 + mh * 64 + mt * 32 + l31;
        int sl = ((ks << 1) + l5) ^ (r & 7);
        return *(const i32x4*)(smem + bi * 32768 + r * 128 + (sl << 4));
    };
    auto ldB32 = [&](int bi, int nh, int ks) -> i32x4 {
        int pr = nh * 128 + wn * 32 + l31;
        int sl = ((ks << 1) + l5) ^ (pr & 7);
        return *(const i32x4*)(smem + 65536 + bi * 32768 + pr * 128 + (sl << 4));
    };

    i32x16 acc[4][2];
#pragma unroll
    for (int i = 0; i < 4; ++i)
#pragma unroll
        for (int j = 0; j < 2; ++j)
#pragma unroll
            for (int k = 0; k < 16; ++k) acc[i][j][k] = 0;

    stageA(0, 0, 0);     stageA(0, 128, 0);
    stageA(0, 64, 0);    stageA(0, 192, 0);
    stageB(0, 0, 0);     stageB(0, 64, 0);
    stageB(0, 128, 0);   stageB(0, 192, 0);
    stageA(1, 0, 128);   stageA(1, 128, 128);
    stageA(1, 64, 128);  stageA(1, 192, 128);
    stageB(1, 128, 128); stageB(1, 192, 128);
    asm volatile("s_waitcnt vmcnt(6)" ::: "memory");
    __builtin_amdgcn_s_barrier();

    i32x4 aR[2][4], bR0[4], bR1[4];

    for (int t = 0; t < 8; ++t) {
        const int bi  = t & 1;
        const int kb1 = (t + 1) << 7;
        const int kb2 = (t + 2) << 7;

#pragma unroll
        for (int mt = 0; mt < 2; ++mt)
#pragma unroll
            for (int ks = 0; ks < 4; ++ks) aR[mt][ks] = ldA32(bi, 0, mt, ks);
#pragma unroll
        for (int ks = 0; ks < 4; ++ks) bR0[ks] = ldB32(bi, 0, ks);
        if (t <= 6) { stageB(bi ^ 1, 0, kb1); stageB(bi ^ 1, 64, kb1); }
        PH32(0, 0, bR0)

#pragma unroll
        for (int ks = 0; ks < 4; ++ks) bR1[ks] = ldB32(bi, 1, ks);
        if (t <= 5) { stageA(bi, 0, kb2); stageA(bi, 128, kb2); }
        PH32(0, 1, bR1)

#pragma unroll
        for (int mt = 0; mt < 2; ++mt)
#pragma unroll
            for (int ks = 0; ks < 4; ++ks) aR[mt][ks] = ldA32(bi, 1, mt, ks);
        PH32(1, 1, bR1)

        if (t <= 5) { stageA(bi, 64, kb2); stageA(bi, 192, kb2);
                      stageB(bi, 128, kb2); stageB(bi, 192, kb2); }
        if (t < 6) asm volatile("s_waitcnt vmcnt(6)" ::: "memory");
        else       asm volatile("s_waitcnt vmcnt(0)" ::: "memory");
        PH32(1, 0, bR0)
    }

    // ---- epilogue: scale in-reg, transpose via LDS, coalesced float4 stores ----
    const float sc = *scale_f;
    float* ep = (float*)smem;               // 128 rows x 256 cols fp32 = 128 KB
    float bv[2];
#pragma unroll
    for (int ni = 0; ni < 2; ++ni) bv[ni] = bias[tn * 256 + wn * 64 + ni * 32 + l31];

#pragma unroll
    for (int half = 0; half < 2; ++half) {
        __syncthreads();                    // previous LDS use (K-loop / prior half reads) done
#pragma unroll
        for (int mi2 = 0; mi2 < 2; ++mi2) {
            const int mi = half * 2 + mi2;
            float fr[16];
#pragma unroll
            for (int r = 0; r < 16; ++r)
                fr[r] = sc * fact[tm * 256 + wm * 128 + mi * 32 + (r & 3) + 8 * (r >> 2) + 4 * l5];
#pragma unroll
            for (int ni = 0; ni < 2; ++ni) {
#pragma unroll
                for (int r = 0; r < 16; ++r) {
                    int rloc = (r & 3) + 8 * (r >> 2) + 4 * l5;        // 0..31
                    int lrow = wm * 64 + mi2 * 32 + rloc;              // 0..127
                    ep[lrow * 256 + wn * 64 + ni * 32 + l31] =
                        (float)acc[mi][ni][r] * fr[r] + bv[ni];
                }
            }
        }
        __syncthreads();
        // stream out 128 rows x 1 KB, one row per wave-iteration, fully coalesced
#pragma unroll
        for (int it = 0; it < 16; ++it) {
            int lrow = wid * 16 + it;
            int grow = tm * 256 + (lrow >> 6) * 128 + half * 64 + (lrow & 63);
            float4 v = *(const float4*)&ep[lrow * 256 + lane * 4];
            *(float4*)&out[(size_t)grow * 1024 + tn * 256 + lane * 4] = v;
        }
    }
}

extern "C" void kernel_launch(void* const* d_in, const int* in_sizes, int n_in,
                              void* d_out, int out_size, void* d_ws, size_t ws_size,
                              hipStream_t stream) {
    const float* x    = (const float*)d_in[0];
    const float* w    = (const float*)d_in[1];
    const float* bias = (const float*)d_in[2];
    float* out = (float*)d_out;
    char* ws = (char*)d_ws;

    double* partials = (double*)ws;
    float*  scale_f  = (float*)(ws + WS_SCALEF);
    float*  fact     = (float*)(ws + WS_FACT);
    int8_t* xq       = (int8_t*)(ws + WS_XQ);
    int8_t* qw       = (int8_t*)(ws + WS_QW);

    k_fused1<<<8448, 256, 0, stream>>>(x, w, xq, fact, partials);
    k_fused2<<<512, 256, 0, stream>>>(w, partials, qw, scale_f);
    k_gemm4<<<512, 512, 0, stream>>>(xq, qw, fact, scale_f, bias, out);
}

// Round 7
// 89.067 us; speedup vs baseline: 1.0534x; 1.0534x over previous
//
#include <hip/hip_runtime.h>
#include <stdint.h>

using i32x4  = __attribute__((ext_vector_type(4))) int;
using i32x16 = __attribute__((ext_vector_type(16))) int;

// ---------------- ws layout ----------------
#define WS_SCALED   2048
#define WS_SCALEF   2056
#define WS_FACT     4096
#define WS_XQ       (1u << 20)
#define WS_QW       ((1u << 20) + (32u << 20))

// ---------------- kernel 1: fused aquant (blocks 0..8191) + wabs partials (8192..8447) ----
__device__ inline int q8pack(float4 f, float as) {
    int a = (int)fminf(fmaxf(rintf(f.x * as), -128.0f), 127.0f);
    int b = (int)fminf(fmaxf(rintf(f.y * as), -128.0f), 127.0f);
    int c = (int)fminf(fmaxf(rintf(f.z * as), -128.0f), 127.0f);
    int d = (int)fminf(fmaxf(rintf(f.w * as), -128.0f), 127.0f);
    return (a & 0xff) | ((b & 0xff) << 8) | ((c & 0xff) << 16) | ((d & 0xff) << 24);
}

__global__ __launch_bounds__(256) void k_fused1(const float* __restrict__ x,
                                                const float* __restrict__ w,
                                                int8_t* __restrict__ xq,
                                                float* __restrict__ fact,
                                                double* __restrict__ partials) {
    int t = threadIdx.x;
    if (blockIdx.x >= 8192) {
        int b = blockIdx.x - 8192;
        const float4* w4 = (const float4*)(w + b * 4096);
        double s = 0.0;
#pragma unroll
        for (int i = 0; i < 4; ++i) {
            float4 v = w4[i * 256 + t];
            s += (double)fabsf(v.x) + (double)fabsf(v.y) +
                 (double)fabsf(v.z) + (double)fabsf(v.w);
        }
#pragma unroll
        for (int off = 32; off > 0; off >>= 1) s += __shfl_down(s, off, 64);
        __shared__ double lds[4];
        if ((t & 63) == 0) lds[t >> 6] = s;
        __syncthreads();
        if (t == 0) partials[b] = ((lds[0] + lds[1]) + (lds[2] + lds[3]));
        return;
    }
    int wid = t >> 6;
    int lane = t & 63;
    int token = blockIdx.x * 4 + wid;
    const float* xr = x + (size_t)token * 1024;
    float4 v[4];
    float m = 0.0f;
#pragma unroll
    for (int c = 0; c < 4; ++c) {
        v[c] = *(const float4*)(xr + c * 256 + lane * 4);
        m = fmaxf(m, fmaxf(fmaxf(fabsf(v[c].x), fabsf(v[c].y)),
                           fmaxf(fabsf(v[c].z), fabsf(v[c].w))));
    }
#pragma unroll
    for (int off = 32; off > 0; off >>= 1) m = fmaxf(m, __shfl_xor(m, off, 64));
    m = fmaxf(m, 1e-5f);
    float as = 127.0f / m;
    int* xqo = (int*)xq;
#pragma unroll
    for (int c = 0; c < 4; ++c)
        xqo[token * 256 + c * 64 + lane] = q8pack(v[c], as);
    if (lane == 0) fact[token] = 1.0f / as;
}

// ---------------- kernel 2: fused scale-reduce (redundant, deterministic) + wquant ----
__global__ __launch_bounds__(256) void k_fused2(const float* __restrict__ w,
                                                const double* __restrict__ partials,
                                                int8_t* __restrict__ qw,
                                                float* __restrict__ scale_f) {
    int t = threadIdx.x;
    double s = partials[t];
#pragma unroll
    for (int off = 32; off > 0; off >>= 1) s += __shfl_down(s, off, 64);
    __shared__ double lds[4];
    if ((t & 63) == 0) lds[t >> 6] = s;
    __syncthreads();
    __shared__ double sc_sh;
    if (t == 0) {
        double m = ((lds[0] + lds[1]) + (lds[2] + lds[3])) / 1048576.0;
        if (m < 1e-5) m = 1e-5;
        sc_sh = m;
        if (blockIdx.x == 0) *scale_f = (float)m;
    }
    __syncthreads();
    double half_s = 0.5 * sc_sh;

    int idx = blockIdx.x * 2048 + t * 8;
    float4 v0 = *(const float4*)(w + idx);
    float4 v1 = *(const float4*)(w + idx + 4);
    float f[8] = {v0.x, v0.y, v0.z, v0.w, v1.x, v1.y, v1.z, v1.w};
    union { char c[8]; int2 p; } u;
#pragma unroll
    for (int i = 0; i < 8; ++i) {
        char q = 0;
        if ((double)fabsf(f[i]) > half_s) q = (f[i] > 0.0f) ? 1 : -1;
        u.c[i] = q;
    }
    *(int2*)(qw + idx) = u.p;
}

// ---------------- kernel 3: i8 MFMA GEMM, 128x256 tile, BK=64, 3-buffer, 2 blocks/CU ----
// A = xq [32768][1024], B = qw [1024][1024]. 8 waves (2M x 4N), per-wave 64x64
// (2x2 of 32x32x32 i8, acc = 64 VGPR). LDS 72 KB: 3 rotating buffers x (A 8KB | B 16KB).
// Per K-tile: {8 ds_read_b128 ; stage batch t+2 (3 gl_lds16) ; vmcnt(3)+lgkmcnt(0) ;
// barrier ; 8 MFMA}. Staging never touches a buffer being read (3-way rotation).
// Swizzle (64B rows, 4 slots): slot ^= (row>>1)&3 -> 8 rows cover all 32 banks.

__device__ __forceinline__ void gl_lds16(const void* g, void* l) {
    __builtin_amdgcn_global_load_lds((const __attribute__((address_space(1))) void*)g,
                                     (__attribute__((address_space(3))) void*)l, 16, 0, 0);
}

__global__ __launch_bounds__(512, 4) void k_gemm5(const int8_t* __restrict__ A,
                                                  const int8_t* __restrict__ B,
                                                  const float* __restrict__ fact,
                                                  const float* __restrict__ scale_f,
                                                  const float* __restrict__ bias,
                                                  float* __restrict__ out) {
    __shared__ int8_t smem[73728];          // 3 x (A 8192 | B 16384)

    const int tid  = threadIdx.x;
    const int lane = tid & 63;
    const int wid  = tid >> 6;
    const int wm   = wid >> 2;              // 0..1
    const int wn   = wid & 3;               // 0..3
    const int l31  = lane & 31;
    const int l5   = lane >> 5;

    // XCD-aware bijective swizzle (1024 % 8 == 0)
    int bid = blockIdx.x;
    int swz = (bid & 7) * 128 + (bid >> 3);
    int tm = swz >> 2;                      // 0..255
    int tn = swz & 3;                       // 0..3

    const int8_t* Ag = A + (size_t)tm * 128 * 1024;
    const int8_t* Bg = B + (size_t)tn * 256 * 1024;

    const int spr = tid >> 2;               // staging row 0..127
    const int ssl = tid & 3;                // staging slot 0..3

    auto stage = [&](int buf, int kb) {     // one batch: A(128 rows) + B(2x128 rows)
        int base = buf * 24576;
        gl_lds16(Ag + (size_t)spr * 1024 + kb + (((ssl ^ ((spr >> 1) & 3))) << 4),
                 smem + base + tid * 16);
        gl_lds16(Bg + (size_t)spr * 1024 + kb + (((ssl ^ ((spr >> 1) & 3))) << 4),
                 smem + base + 8192 + tid * 16);
        int pr2 = 128 + spr;
        gl_lds16(Bg + (size_t)pr2 * 1024 + kb + (((ssl ^ ((pr2 >> 1) & 3))) << 4),
                 smem + base + 8192 + 8192 + tid * 16);
    };
    auto ldA = [&](int buf, int mt, int ks) -> i32x4 {
        int r = wm * 64 + mt * 32 + l31;
        int s = ((ks << 1) | l5) ^ ((r >> 1) & 3);
        return *(const i32x4*)(smem + buf * 24576 + r * 64 + (s << 4));
    };
    auto ldB = [&](int buf, int nt, int ks) -> i32x4 {
        int r = wn * 64 + nt * 32 + l31;
        int s = ((ks << 1) | l5) ^ ((r >> 1) & 3);
        return *(const i32x4*)(smem + buf * 24576 + 8192 + r * 64 + (s << 4));
    };

    i32x16 acc[2][2];
#pragma unroll
    for (int i = 0; i < 2; ++i)
#pragma unroll
        for (int j = 0; j < 2; ++j)
#pragma unroll
            for (int k = 0; k < 16; ++k) acc[i][j][k] = 0;

    // prologue: batches for K-tiles 0 and 1
    stage(0, 0);
    stage(1, 64);
    asm volatile("s_waitcnt vmcnt(3)" ::: "memory");   // batch0 landed
    __builtin_amdgcn_s_barrier();

    i32x4 aR[2][2], bR[2][2];

#pragma unroll
    for (int t = 0; t < 16; ++t) {
        const int buf = t % 3;

#pragma unroll
        for (int mt = 0; mt < 2; ++mt)
#pragma unroll
            for (int ks = 0; ks < 2; ++ks) aR[mt][ks] = ldA(buf, mt, ks);
#pragma unroll
        for (int nt = 0; nt < 2; ++nt)
#pragma unroll
            for (int ks = 0; ks < 2; ++ks) bR[nt][ks] = ldB(buf, nt, ks);

        if (t < 14) stage((t + 2) % 3, (t + 2) * 64);

        if (t <= 13) asm volatile("s_waitcnt vmcnt(3) lgkmcnt(0)" ::: "memory");
        else         asm volatile("s_waitcnt vmcnt(0) lgkmcnt(0)" ::: "memory");
        __builtin_amdgcn_s_barrier();

        __builtin_amdgcn_s_setprio(1);
#pragma unroll
        for (int ks = 0; ks < 2; ++ks)
#pragma unroll
            for (int mt = 0; mt < 2; ++mt)
#pragma unroll
                for (int nt = 0; nt < 2; ++nt)
                    acc[mt][nt] = __builtin_amdgcn_mfma_i32_32x32x32_i8(
                        aR[mt][ks], bR[nt][ks], acc[mt][nt], 0, 0, 0);
        __builtin_amdgcn_s_setprio(0);
    }

    // ---- epilogue: direct stores (format proven non-limiting r4/r6) ----
    const float sc = *scale_f;
#pragma unroll
    for (int mt = 0; mt < 2; ++mt) {
        int rbase = tm * 128 + wm * 64 + mt * 32 + 4 * l5;
        float fr[16];
#pragma unroll
        for (int r = 0; r < 16; ++r)
            fr[r] = sc * fact[rbase + (r & 3) + 8 * (r >> 2)];
#pragma unroll
        for (int nt = 0; nt < 2; ++nt) {
            int c = tn * 256 + wn * 64 + nt * 32 + l31;
            float bv = bias[c];
#pragma unroll
            for (int r = 0; r < 16; ++r) {
                int row = rbase + (r & 3) + 8 * (r >> 2);
                out[(size_t)row * 1024 + c] = (float)acc[mt][nt][r] * fr[r] + bv;
            }
        }
    }
}

extern "C" void kernel_launch(void* const* d_in, const int* in_sizes, int n_in,
                              void* d_out, int out_size, void* d_ws, size_t ws_size,
                              hipStream_t stream) {
    const float* x    = (const float*)d_in[0];
    const float* w    = (const float*)d_in[1];
    const float* bias = (const float*)d_in[2];
    float* out = (float*)d_out;
    char* ws = (char*)d_ws;

    double* partials = (double*)ws;
    float*  scale_f  = (float*)(ws + WS_SCALEF);
    float*  fact     = (float*)(ws + WS_FACT);
    int8_t* xq       = (int8_t*)(ws + WS_XQ);
    int8_t* qw       = (int8_t*)(ws + WS_QW);

    k_fused1<<<8448, 256, 0, stream>>>(x, w, xq, fact, partials);
    k_fused2<<<512, 256, 0, stream>>>(w, partials, qw, scale_f);
    k_gemm5<<<1024, 512, 0, stream>>>(xq, qw, fact, scale_f, bias, out);
}